// Round 7
// baseline (70.806 us; speedup 1.0000x reference)
//
#include <hip/hip_runtime.h>
#include <hip/hip_bf16.h>

// Problem: B=32, L=256, K=8, E=768, V=50000 ; M = B*L = 8192
// inputs: hidden [M,E] f32, similar_words [M,K] int32, word2vec [V,E] f32, weight [E,E] f32
// out:    [M,E] f32
//
// Two dispatches:
//  1) prep: hidden -> Af2 f16 [E/8][M][8] (k-slot-major), W -> Wt2 f16 [E/8][E][8] (W^T, k-slot-major)
//  2) fused: per block of 32 rows: qproj = A@W via mfma_32x32x16_f16
//     (A panel resident in LDS, B full-N k-slices dbuf, stage-early, Q kept in
//     LDS by reusing B-buf0), then gather/softmax/weighted-sum from LDS q.
// K-slot-major layouts make global_load_lds sources coalesced and ALL LDS
// fragment reads 1024B-contiguous (conflict-free, no swizzle).

typedef __attribute__((ext_vector_type(8))) _Float16 f16x8;    // 4 VGPR
typedef __attribute__((ext_vector_type(16))) float f32x16;     // 32x32 acc

__device__ __forceinline__ unsigned short f2h(float f) {
    _Float16 h = (_Float16)f;
    return __builtin_bit_cast(unsigned short, h);
}
__device__ __forceinline__ float h2f(unsigned short u) {
    return (float)__builtin_bit_cast(_Float16, u);
}

// async global->LDS, 16B/lane; LDS dest = wave-uniform base + lane*16 (rule 21).
__device__ __forceinline__ void gload16(const void* g, void* l) {
    __builtin_amdgcn_global_load_lds(
        (const __attribute__((address_space(1))) unsigned int*)g,
        (__attribute__((address_space(3))) unsigned int*)l, 16, 0, 0);
}

// ---------------- prep: f32 -> f16, k-slot-major transposed layouts ----------------
// blocks [0, atiles): hidden 32x32 tile -> Af2[e8][m][8]
// blocks [atiles, ..): W 32x32 tile     -> Wt2[k8][n][8]  (= W^T, K-contig chunks)
__global__ __launch_bounds__(256) void prep(const float* __restrict__ hidden,
                                            const float* __restrict__ W,
                                            unsigned short* __restrict__ Af2,
                                            unsigned short* __restrict__ Wt2,
                                            int M, int atiles) {
    __shared__ unsigned short tA[32][36];
    __shared__ float tW[32][33];
    const int bid = blockIdx.x;
    if (bid < atiles) {
        const int mtiles = M / 32;
        const int m0 = (bid % mtiles) * 32, e0 = (bid / mtiles) * 32;
        const int ty = threadIdx.x >> 3, tx = threadIdx.x & 7;   // 32 x 8
        const float4* h4 = (const float4*)hidden;
        float4 v = h4[(size_t)(m0 + ty) * 192 + (e0 >> 2) + tx];
        tA[ty][tx * 4 + 0] = f2h(v.x);
        tA[ty][tx * 4 + 1] = f2h(v.y);
        tA[ty][tx * 4 + 2] = f2h(v.z);
        tA[ty][tx * 4 + 3] = f2h(v.w);
        __syncthreads();
        if (threadIdx.x < 128) {
            const int m = threadIdx.x & 31, e8 = threadIdx.x >> 5;   // chunk (m, e8)
            uint2 lo = *(const uint2*)&tA[m][e8 * 8];
            uint2 hi = *(const uint2*)&tA[m][e8 * 8 + 4];
            uint4 pk = {lo.x, lo.y, hi.x, hi.y};
            *(uint4*)(Af2 + ((size_t)((e0 >> 3) + e8) * M + m0 + m) * 8) = pk;
        }
    } else {
        const int wid = bid - atiles;
        const int bk = (wid % 24) * 32, bn = (wid / 24) * 32;
        const int tx = threadIdx.x & 31, ty = threadIdx.x >> 5;   // 32 x 8
#pragma unroll
        for (int r = ty; r < 32; r += 8)
            tW[r][tx] = W[(size_t)(bk + r) * 768 + bn + tx];
        __syncthreads();
        if (threadIdx.x < 128) {
            const int nr = threadIdx.x & 31, k8 = threadIdx.x >> 5;
            unsigned int u[4];
#pragma unroll
            for (int p = 0; p < 4; ++p) {
                unsigned int a = f2h(tW[k8 * 8 + 2 * p][nr]);
                unsigned int b = f2h(tW[k8 * 8 + 2 * p + 1][nr]);
                u[p] = a | (b << 16);
            }
            uint4 pk = {u[0], u[1], u[2], u[3]};
            *(uint4*)(Wt2 + ((size_t)((bk >> 3) + k8) * 768 + bn + nr) * 8) = pk;
        }
    }
}

// ---------------- fused GEMM (32x32x16 MFMA) + gather/softmax/output ----------------
__global__ __launch_bounds__(512, 2) void fused(
        const unsigned short* __restrict__ Af2,   // [96][M][8]
        const unsigned short* __restrict__ Wt2,   // [96][768][8]
        const int* __restrict__ sws,
        const float* __restrict__ w2v,
        float* __restrict__ out, int M) {

    __shared__ unsigned short ldsB[2][24576];   // [4 kslot][768 col][8]  2x48 KiB
    __shared__ unsigned short ldsA[24576];      // [96 kslot][32 m][8]      48 KiB

    const int tid = threadIdx.x, lane = tid & 63, w = tid >> 6;  // 8 waves
    const int l31 = lane & 31, lh = lane >> 5;
    const int rows0 = blockIdx.x * 32;

    // ---- stage A panel once (3072 chunks, 6/thread), sources coalesced ----
#pragma unroll
    for (int i = 0; i < 6; ++i) {
        int s = w * 384 + i * 64 + lane;                   // chunk = k8*32 + m
        gload16(Af2 + ((size_t)(s >> 5) * M + rows0 + (s & 31)) * 8,
                &ldsA[(size_t)s * 8]);
    }
    // ---- B tile stage: [4 kslot][768 col] for k0 (32 k-elems) ----
    auto STAGEB = [&](int k0, int buf) {
#pragma unroll
        for (int i = 0; i < 6; ++i) {
            int base = w * 384 + i * 64;                    // 64-chunk run, ks uniform
            int ks = base / 768;
            int col = base % 768 + lane;
            gload16(Wt2 + ((size_t)(k0 * 4 + ks) * 768 + col) * 8,
                    &ldsB[buf][(size_t)(base + lane) * 8]);
        }
    };
    STAGEB(0, 0);

    f32x16 acc0, acc1, acc2;
#pragma unroll
    for (int r = 0; r < 16; ++r) { acc0[r] = 0.f; acc1[r] = 0.f; acc2[r] = 0.f; }

    __syncthreads();   // drain: A + B0 ready

    for (int k0 = 0; k0 < 24; ++k0) {
        const int buf = k0 & 1;
        if (k0 < 23) STAGEB(k0 + 1, buf ^ 1);   // issue-early, flies during compute
#pragma unroll
        for (int kc = 0; kc < 2; ++kc) {
            const int ksl = kc * 2 + lh;        // this lane-half's k-slot (0..3)
            f16x8 a  = *(const f16x8*)&ldsA[((size_t)(k0 * 4 + ksl) * 32 + l31) * 8];
            f16x8 b0 = *(const f16x8*)&ldsB[buf][((size_t)ksl * 768 + w * 96      + l31) * 8];
            f16x8 b1 = *(const f16x8*)&ldsB[buf][((size_t)ksl * 768 + w * 96 + 32 + l31) * 8];
            f16x8 b2 = *(const f16x8*)&ldsB[buf][((size_t)ksl * 768 + w * 96 + 64 + l31) * 8];
            acc0 = __builtin_amdgcn_mfma_f32_32x32x16_f16(a, b0, acc0, 0, 0, 0);
            acc1 = __builtin_amdgcn_mfma_f32_32x32x16_f16(a, b1, acc1, 0, 0, 0);
            acc2 = __builtin_amdgcn_mfma_f32_32x32x16_f16(a, b2, acc2, 0, 0, 0);
        }
        __syncthreads();   // drains stage (vmcnt0) + all waves done with buf
    }

    // ---- Q (f16) into ldsB[0] — free after last iteration (buf=1 computed last)
    // C/D layout 32x32 [m74/m101]: col = lane&31, row = (reg&3)+8*(reg>>2)+4*(lane>>5)
    unsigned short* ldsQ = &ldsB[0][0];   // [32][768]
#pragma unroll
    for (int r = 0; r < 16; ++r) {
        const int row = (r & 3) + 8 * (r >> 2) + 4 * lh;
        ldsQ[row * 768 + w * 96      + l31] = f2h(acc0[r]);
        ldsQ[row * 768 + w * 96 + 32 + l31] = f2h(acc1[r]);
        ldsQ[row * 768 + w * 96 + 64 + l31] = f2h(acc2[r]);
    }
    __syncthreads();

    // ---- attention: wave per row, 4 rows/wave (proven r1-r6 structure) ----
    for (int rr = 0; rr < 4; ++rr) {
        const int r = w * 4 + rr;
        const size_t grow = (size_t)rows0 + r;

        float4 q[3];
#pragma unroll
        for (int j = 0; j < 3; ++j) {
            ushort4 h = *(const ushort4*)&ldsQ[(size_t)r * 768 + (j * 64 + lane) * 4];
            q[j].x = h2f(h.x); q[j].y = h2f(h.y); q[j].z = h2f(h.z); q[j].w = h2f(h.w);
        }

        float4 ks[8][3];
        float dot[8];
#pragma unroll
        for (int k = 0; k < 8; ++k) {
            int id = sws[grow * 8 + k];
            const float4* kp = (const float4*)(w2v + (size_t)id * 768);
            float d = 0.f;
#pragma unroll
            for (int j = 0; j < 3; ++j) {
                float4 v = kp[j * 64 + lane];
                ks[k][j] = v;
                d += q[j].x * v.x;
                d += q[j].y * v.y;
                d += q[j].z * v.z;
                d += q[j].w * v.w;
            }
            dot[k] = d;
        }
#pragma unroll
        for (int k = 0; k < 8; ++k) {
            float d = dot[k];
#pragma unroll
            for (int m = 1; m < 64; m <<= 1) d += __shfl_xor(d, m);
            dot[k] = d;
        }
        float mx = dot[0];
#pragma unroll
        for (int k = 1; k < 8; ++k) mx = fmaxf(mx, dot[k]);
        float wt[8];
        float s = 0.f;
#pragma unroll
        for (int k = 0; k < 8; ++k) { wt[k] = __expf(dot[k] - mx); s += wt[k]; }
        const float inv = 1.f / s;

        float4 o[3];
#pragma unroll
        for (int j = 0; j < 3; ++j) { o[j].x = 0.f; o[j].y = 0.f; o[j].z = 0.f; o[j].w = 0.f; }
#pragma unroll
        for (int k = 0; k < 8; ++k) {
            const float a = wt[k] * inv;
#pragma unroll
            for (int j = 0; j < 3; ++j) {
                o[j].x += a * ks[k][j].x;
                o[j].y += a * ks[k][j].y;
                o[j].z += a * ks[k][j].z;
                o[j].w += a * ks[k][j].w;
            }
        }
        float4* o4 = (float4*)(out + grow * 768);
#pragma unroll
        for (int j = 0; j < 3; ++j) o4[j * 64 + lane] = o[j];
    }
}

// ---------------- fallback f32 path (if ws too small) ----------------
#define GM_BM 128
#define GM_BN 64
#define GM_BK 16
#define GM_TM 8
#define GM_TN 4

__global__ __launch_bounds__(256) void gemm_qproj(const float* __restrict__ A,
                                                  const float* __restrict__ B,
                                                  float* __restrict__ C,
                                                  int M, int N, int K) {
    __shared__ float As[GM_BK][GM_BM];
    __shared__ float Bs[GM_BK][GM_BN];
    const int tid = threadIdx.x;
    const int tx = tid & 15;
    const int ty = tid >> 4;
    const int bm = blockIdx.x * GM_BM;
    const int bn = blockIdx.y * GM_BN;
    float acc[GM_TM][GM_TN];
#pragma unroll
    for (int i = 0; i < GM_TM; ++i)
#pragma unroll
        for (int j = 0; j < GM_TN; ++j) acc[i][j] = 0.f;
    for (int k0 = 0; k0 < K; k0 += GM_BK) {
#pragma unroll
        for (int i = 0; i < 2; ++i) {
            int idx = tid * 2 + i;
            int row = idx >> 2;
            int c4  = idx & 3;
            float4 v = *(const float4*)(A + (size_t)(bm + row) * K + k0 + c4 * 4);
            As[c4 * 4 + 0][row] = v.x;
            As[c4 * 4 + 1][row] = v.y;
            As[c4 * 4 + 2][row] = v.z;
            As[c4 * 4 + 3][row] = v.w;
        }
        {
            int row = tid >> 4;
            int c4  = tid & 15;
            float4 v = *(const float4*)(B + (size_t)(k0 + row) * N + bn + c4 * 4);
            *(float4*)&Bs[row][c4 * 4] = v;
        }
        __syncthreads();
#pragma unroll
        for (int k = 0; k < GM_BK; ++k) {
            float a[GM_TM], b[GM_TN];
#pragma unroll
            for (int i = 0; i < GM_TM; ++i) a[i] = As[k][ty * GM_TM + i];
#pragma unroll
            for (int j = 0; j < GM_TN; ++j) b[j] = Bs[k][tx * GM_TN + j];
#pragma unroll
            for (int i = 0; i < GM_TM; ++i)
#pragma unroll
                for (int j = 0; j < GM_TN; ++j) acc[i][j] += a[i] * b[j];
        }
        __syncthreads();
    }
#pragma unroll
    for (int i = 0; i < GM_TM; ++i) {
        float4 v;
        v.x = acc[i][0]; v.y = acc[i][1]; v.z = acc[i][2]; v.w = acc[i][3];
        *(float4*)(C + (size_t)(bm + ty * GM_TM + i) * N + bn + tx * GM_TN) = v;
    }
}

__global__ __launch_bounds__(256) void attn_fused(const float* __restrict__ qproj,
                                                  const int* __restrict__ sws,
                                                  const float* __restrict__ w2v,
                                                  float* __restrict__ out) {
    const int wave = threadIdx.x >> 6;
    const int lane = threadIdx.x & 63;
    const size_t row = (size_t)blockIdx.x * 4 + wave;

    const float4* q4 = (const float4*)(qproj + row * 768);
    float4 q[3];
#pragma unroll
    for (int j = 0; j < 3; ++j) q[j] = q4[j * 64 + lane];

    float4 ks[8][3];
    float dot[8];
#pragma unroll
    for (int k = 0; k < 8; ++k) {
        int id = sws[row * 8 + k];
        const float4* kp = (const float4*)(w2v + (size_t)id * 768);
        float d = 0.f;
#pragma unroll
        for (int j = 0; j < 3; ++j) {
            float4 v = kp[j * 64 + lane];
            ks[k][j] = v;
            d += q[j].x * v.x + q[j].y * v.y + q[j].z * v.z + q[j].w * v.w;
        }
        dot[k] = d;
    }
#pragma unroll
    for (int k = 0; k < 8; ++k) {
        float d = dot[k];
#pragma unroll
        for (int m = 1; m < 64; m <<= 1) d += __shfl_xor(d, m);
        dot[k] = d;
    }
    float mx = dot[0];
#pragma unroll
    for (int k = 1; k < 8; ++k) mx = fmaxf(mx, dot[k]);
    float wq[8];
    float s = 0.f;
#pragma unroll
    for (int k = 0; k < 8; ++k) { wq[k] = __expf(dot[k] - mx); s += wq[k]; }
    const float inv = 1.f / s;

    float4 o[3];
#pragma unroll
    for (int j = 0; j < 3; ++j) { o[j].x = 0.f; o[j].y = 0.f; o[j].z = 0.f; o[j].w = 0.f; }
#pragma unroll
    for (int k = 0; k < 8; ++k) {
        const float a = wq[k] * inv;
#pragma unroll
        for (int j = 0; j < 3; ++j) {
            o[j].x += a * ks[k][j].x;
            o[j].y += a * ks[k][j].y;
            o[j].z += a * ks[k][j].z;
            o[j].w += a * ks[k][j].w;
        }
    }
    float4* o4 = (float4*)(out + row * 768);
#pragma unroll
    for (int j = 0; j < 3; ++j) o4[j * 64 + lane] = o[j];
}

extern "C" void kernel_launch(void* const* d_in, const int* in_sizes, int n_in,
                              void* d_out, int out_size, void* d_ws, size_t ws_size,
                              hipStream_t stream) {
    const float* hidden = (const float*)d_in[0];
    const int*   sws    = (const int*)d_in[1];
    const float* w2v    = (const float*)d_in[2];
    const float* weight = (const float*)d_in[3];
    float*       out    = (float*)d_out;

    const int E = 768;
    const int M = in_sizes[0] / E;            // 8192

    const size_t szA = (size_t)M * E;          // elements
    const size_t szW = (size_t)E * E;
    const size_t need = (szA + szW) * sizeof(unsigned short);   // ~13.8 MB

    if (ws_size >= need && (M % 32) == 0) {
        unsigned short* Af2 = (unsigned short*)d_ws;   // [E/8][M][8]
        unsigned short* Wt2 = Af2 + szA;                // [E/8][E][8]

        const int atiles = (M / 32) * (E / 32);         // 6144
        const int wtiles = (E / 32) * (E / 32);         // 576
        prep<<<atiles + wtiles, 256, 0, stream>>>(hidden, weight, Af2, Wt2, M, atiles);

        fused<<<M / 32, 512, 0, stream>>>(Af2, Wt2, sws, w2v, out, M);
    } else {
        float* qproj = out;
        dim3 ggrid(M / GM_BM, E / GM_BN);
        gemm_qproj<<<ggrid, 256, 0, stream>>>(hidden, weight, qproj, M, E, E);
        attn_fused<<<dim3(M / 4), 256, 0, stream>>>(qproj, sws, w2v, out);
    }
}